// Round 9
// baseline (141793.335 us; speedup 1.0000x reference)
//
#include <hip/hip_runtime.h>
#include <math.h>

#define T_STEPS 32768
#define HID 2048
#define EMB 2048

// ---------------------------------------------------------------------------
// Kernel A: XP[m] = X[m] @ Wx + b  (m = 0..T-2) -> XPout[m*HID + ...].
// Fast path: XPout = ws XP buffer. Fallback: XPout = H + HID (in-place R3).
// ---------------------------------------------------------------------------
#define BM 64
#define BN 64
#define BK 16

__global__ __launch_bounds__(256) void xproj_gemm(const float* __restrict__ X,
                                                  const float* __restrict__ Wx,
                                                  const float* __restrict__ bias,
                                                  float* __restrict__ XPout)
{
    __shared__ __align__(16) float As[BK][BM];
    __shared__ __align__(16) float Bs[BK][BN];

    const int tid = threadIdx.x;
    const int m0 = blockIdx.y * BM;
    const int n0 = blockIdx.x * BN;

    const int tn = tid & 15;
    const int tm = tid >> 4;
    const int am = tid >> 2;
    const int ak = (tid & 3) << 2;
    const int bk = tid >> 4;
    const int bn = (tid & 15) << 2;

    const int arow = m0 + am;
    const bool aval = arow < (T_STEPS - 1);

    float acc[4][4];
#pragma unroll
    for (int i = 0; i < 4; ++i)
#pragma unroll
        for (int j = 0; j < 4; ++j) acc[i][j] = 0.f;

    for (int k0 = 0; k0 < EMB; k0 += BK) {
        float4 av = make_float4(0.f, 0.f, 0.f, 0.f);
        if (aval) av = *(const float4*)&X[(size_t)arow * EMB + k0 + ak];
        float4 bv = *(const float4*)&Wx[(size_t)(k0 + bk) * HID + n0 + bn];

        __syncthreads();
        As[ak + 0][am] = av.x;
        As[ak + 1][am] = av.y;
        As[ak + 2][am] = av.z;
        As[ak + 3][am] = av.w;
        *(float4*)&Bs[bk][bn] = bv;
        __syncthreads();

#pragma unroll
        for (int k = 0; k < BK; ++k) {
            float4 a4 = *(const float4*)&As[k][tm << 2];
            float4 b4 = *(const float4*)&Bs[k][tn << 2];
            acc[0][0] += a4.x * b4.x; acc[0][1] += a4.x * b4.y;
            acc[0][2] += a4.x * b4.z; acc[0][3] += a4.x * b4.w;
            acc[1][0] += a4.y * b4.x; acc[1][1] += a4.y * b4.y;
            acc[1][2] += a4.y * b4.z; acc[1][3] += a4.y * b4.w;
            acc[2][0] += a4.z * b4.x; acc[2][1] += a4.z * b4.y;
            acc[2][2] += a4.z * b4.z; acc[2][3] += a4.z * b4.w;
            acc[3][0] += a4.w * b4.x; acc[3][1] += a4.w * b4.y;
            acc[3][2] += a4.w * b4.z; acc[3][3] += a4.w * b4.w;
        }
    }

    float4 bb = *(const float4*)&bias[n0 + (tn << 2)];
#pragma unroll
    for (int i = 0; i < 4; ++i) {
        int m = m0 + (tm << 2) + i;
        if (m < T_STEPS - 1) {
            float4 o;
            o.x = acc[i][0] + bb.x;
            o.y = acc[i][1] + bb.y;
            o.z = acc[i][2] + bb.z;
            o.w = acc[i][3] + bb.w;
            *(float4*)&XPout[(size_t)m * HID + n0 + (tn << 2)] = o;
        }
    }
}

// ---------------------------------------------------------------------------
typedef int v4i __attribute__((ext_vector_type(4)));
typedef int v2i __attribute__((ext_vector_type(2)));

__device__ __forceinline__ float dot4(float4 a, float4 b)
{
    return a.x * b.x + a.y * b.y + a.z * b.z + a.w * b.w;
}

__device__ __forceinline__ void poll4_sc0(const void* p, v4i& a, v4i& b, v4i& c, v4i& d)
{
    asm volatile("global_load_dwordx4 %0, %4, off sc0\n\t"
                 "global_load_dwordx4 %1, %4, off offset:16 sc0\n\t"
                 "global_load_dwordx4 %2, %4, off offset:32 sc0\n\t"
                 "global_load_dwordx4 %3, %4, off offset:48 sc0\n\t"
                 "s_waitcnt vmcnt(0)"
                 : "=&v"(a), "=&v"(b), "=&v"(c), "=&v"(d) : "v"(p) : "memory");
}
__device__ __forceinline__ void poll4_sys(const void* p, v4i& a, v4i& b, v4i& c, v4i& d)
{
    asm volatile("global_load_dwordx4 %0, %4, off sc0 sc1\n\t"
                 "global_load_dwordx4 %1, %4, off offset:16 sc0 sc1\n\t"
                 "global_load_dwordx4 %2, %4, off offset:32 sc0 sc1\n\t"
                 "global_load_dwordx4 %3, %4, off offset:48 sc0 sc1\n\t"
                 "s_waitcnt vmcnt(0)"
                 : "=&v"(a), "=&v"(b), "=&v"(c), "=&v"(d) : "v"(p) : "memory");
}
__device__ __forceinline__ void st8_sc0(void* p, v2i v)
{
    asm volatile("global_store_dwordx2 %0, %1, off sc0" :: "v"(p), "v"(v) : "memory");
}
__device__ __forceinline__ void st8_sys(void* p, v2i v)
{
    asm volatile("global_store_dwordx2 %0, %1, off sc0 sc1" :: "v"(p), "v"(v) : "memory");
}

__device__ __forceinline__ unsigned short bf16rne(float f)
{
    unsigned u = __float_as_uint(f);
    u += 0x7fffu + ((u >> 16) & 1u);
    return (unsigned short)(u >> 16);
}
__device__ __forceinline__ float bfup(unsigned short s)
{
    return __uint_as_float((unsigned)s << 16);
}

// ---------------------------------------------------------------------------
// Kernel B-fast: 8 replicated groups x 32 blocks x 256 thr. Total LDS 81 KB
// (UNDER the 88 KB proven-cooperative ceiling; R4-R7's >=132 KB never
// launched). Per block: 64 cols. Weights rows 0..1535 fp32 in VGPRs (384
// regs; launch_bounds(256,1) -> 512 budget, no spill), rows 1536..2047 bf16
// in LDS (64 KB). Group g=blockIdx&7 (RR dispatch => one XCD); intra-group
// self-announcing {val,step} handshake: publisher dual-stores (sc0 own-L2 +
// sc0 sc1 IF$); consumer polls sc0 with every-16th-round system probe
// (stateless: co-located => pure L2 speed; wrong placement => correct via
// IF$ probes; NO hang mode, NO sticky state). xp from read-only ws XP.
// Only group 0 writes H. Parity double-buffer + poll certificate; 2
// barriers/step.
// ---------------------------------------------------------------------------
__global__ __launch_bounds__(256, 1) void rnn_scan_fast(const float* __restrict__ Wh,
                                                        const float* __restrict__ XP,
                                                        float* __restrict__ H,
                                                        unsigned long long* __restrict__ hcomm)
{
    __shared__ __align__(16) ushort4 Wl2b[128][64];  // 64 KB bf16, rows 1536..2047
    __shared__ __align__(16) float hlds[2][HID];     // 16 KB parity staging
    __shared__ float pacc[4][64];                    // 1 KB cross-wave partials

    const int tid = threadIdx.x;
    const int wave = tid >> 6;            // 0..3
    const int lane = tid & 63;
    const int g = blockIdx.x & 7;         // replica group (XCD under RR dispatch)
    const int rank = blockIdx.x >> 3;     // 0..31
    const int bc0 = rank * 64;            // block's 64 columns
    unsigned long long* hcg = hcomm + (size_t)g * (2 * HID);

    // ---- VGPR weights: rows [384*wave, +384), col bc0+lane (static indices)
    float4 wreg[96];
    {
        const float* wp = Wh + (size_t)(384 * wave) * HID + bc0 + lane;
#pragma unroll
        for (int i = 0; i < 96; ++i) {
            wreg[i].x = wp[(size_t)(4 * i + 0) * HID];
            wreg[i].y = wp[(size_t)(4 * i + 1) * HID];
            wreg[i].z = wp[(size_t)(4 * i + 2) * HID];
            wreg[i].w = wp[(size_t)(3 + 4 * i) * HID];
        }
    }
    // ---- LDS bf16 weights: Wl2b[r4][c] = rows 1536+4*r4..+3, col bc0+c (RNE)
    for (int k = 0; k < 32; ++k) {
        int id = k * 256 + tid;           // 0..8191
        int r4 = id >> 6, c = id & 63;
        const float* p = Wh + (size_t)(1536 + 4 * r4) * HID + bc0 + c;
        ushort4 u;
        u.x = bf16rne(p[0]);
        u.y = bf16rne(p[(size_t)HID]);
        u.z = bf16rne(p[2 * (size_t)HID]);
        u.w = bf16rne(p[3 * (size_t)HID]);
        Wl2b[r4][c] = u;
    }
    __syncthreads();

    for (int t = 0; t < T_STEPS - 1; ++t) {
        const int par = t & 1;

        // xp prefetch from read-only XP (latency hides under the poll)
        float xpv = 0.f;
        if (wave == 0) xpv = XP[(size_t)t * HID + bc0 + lane];

        // ---- poll own 8 {val,step} entries of h_t (64B, one vmcnt wait)
        const char* pb = (const char*)hcg + (((size_t)par * HID + 8 * (size_t)tid) << 3);
        v4i e0, e1, e2, e3;
        int round = 0;
        for (;;) {
            if ((round & 15) == 15) poll4_sys(pb, e0, e1, e2, e3);
            else                    poll4_sc0(pb, e0, e1, e2, e3);
            if (((e0.y ^ t) | (e0.w ^ t) | (e1.y ^ t) | (e1.w ^ t) |
                 (e2.y ^ t) | (e2.w ^ t) | (e3.y ^ t) | (e3.w ^ t)) == 0) break;
            ++round;
        }

        v4i h0; h0.x = e0.x; h0.y = e0.z; h0.z = e1.x; h0.w = e1.z;
        v4i h1; h1.x = e2.x; h1.y = e2.z; h1.z = e3.x; h1.w = e3.z;
        *(v4i*)&hlds[par][8 * tid] = h0;
        *(v4i*)&hlds[par][8 * tid + 4] = h1;
        __syncthreads();   // barrier 1: h_t staged; poll certificate

        // ---- dot(h_t, Wh[:, bc0+lane]); h reads are wave-uniform broadcasts
        const float* hb = hlds[par];
        const float* hbr = &hb[384 * wave];
        float a0 = 0.f, a1 = 0.f, a2 = 0.f, a3 = 0.f;
#pragma unroll
        for (int i = 0; i < 96; i += 4) {
            a0 += dot4(wreg[i],     *(const float4*)&hbr[4 * i]);
            a1 += dot4(wreg[i + 1], *(const float4*)&hbr[4 * i + 4]);
            a2 += dot4(wreg[i + 2], *(const float4*)&hbr[4 * i + 8]);
            a3 += dot4(wreg[i + 3], *(const float4*)&hbr[4 * i + 12]);
        }
        float b0 = 0.f, b1 = 0.f;
#pragma unroll
        for (int j = 0; j < 32; j += 2) {
            const int r4 = 32 * wave + j;
            ushort4 ua = Wl2b[r4][lane];        // 8B/lane, 2-way bank alias (free)
            ushort4 ub = Wl2b[r4 + 1][lane];
            float4 qa = *(const float4*)&hb[1536 + 4 * r4];
            float4 qb = *(const float4*)&hb[1536 + 4 * r4 + 4];
            b0 += bfup(ua.x) * qa.x + bfup(ua.y) * qa.y
                + bfup(ua.z) * qa.z + bfup(ua.w) * qa.w;
            b1 += bfup(ub.x) * qb.x + bfup(ub.y) * qb.y
                + bfup(ub.z) * qb.z + bfup(ub.w) * qb.w;
        }
        pacc[wave][lane] = ((a0 + a1) + (a2 + a3)) + (b0 + b1);
        __syncthreads();   // barrier 2: partials ready (reuse guarded by barrier 1)

        if (wave == 0) {
            float tot = pacc[0][lane] + pacc[1][lane] + pacc[2][lane] + pacc[3][lane];
            float hv = tanhf(xpv + tot);
            v2i e; e.x = __float_as_int(hv); e.y = t + 1;
            char* pa = (char*)hcg + (((size_t)(par ^ 1) * HID + bc0 + lane) << 3);
            st8_sc0(pa, e);   // own-L2 copy for co-located peers
            st8_sys(pa, e);   // IF$ copy for any cross-XCD poller
            if (g == 0) H[(size_t)(t + 1) * HID + bc0 + lane] = hv;
        }
    }
}

// ---------------------------------------------------------------------------
// Kernel B-fallback: verbatim R3 scan (PASSED at 139.8 ms).
// ---------------------------------------------------------------------------
#define NBLK_R3 64
#define TPB_R3 1024
#define CPB_R3 32
#define CPW_R3 2

__device__ __forceinline__ v4i uncached_load16(const void* p)
{
    v4i r;
    asm volatile("global_load_dwordx4 %0, %1, off sc0 sc1\n\t"
                 "s_waitcnt vmcnt(0)"
                 : "=v"(r) : "v"(p) : "memory");
    return r;
}
__device__ __forceinline__ void uncached_store16(void* p, v4i v)
{
    asm volatile("global_store_dwordx4 %0, %1, off sc0 sc1"
                 :: "v"(p), "v"(v) : "memory");
}

__global__ __launch_bounds__(TPB_R3, 4) void rnn_scan_r3(const float* __restrict__ Wh,
                                                         float* __restrict__ H,
                                                         unsigned long long* __restrict__ hcomm)
{
    __shared__ __align__(16) float hlds[2][HID];
    __shared__ float pad[18432];

    const int tid = threadIdx.x;
    const int wave = tid >> 6;
    const int lane = tid & 63;
    const int c0 = blockIdx.x * CPB_R3 + wave * CPW_R3;

    if ((((size_t)hcomm) >> 22) & 1) ((volatile float*)pad)[tid] = 0.f;

    float4 w0[8], w1[8];
#pragma unroll
    for (int k = 0; k < 8; ++k) {
        const int r = 4 * lane + 256 * k;
        const float* p = Wh + (size_t)r * HID + c0;
        w0[k].x = p[0];                     w1[k].x = p[1];
        w0[k].y = p[(size_t)HID];           w1[k].y = p[(size_t)HID + 1];
        w0[k].z = p[(size_t)(2 * HID)];     w1[k].z = p[(size_t)(2 * HID) + 1];
        w0[k].w = p[(size_t)(3 * HID)];     w1[k].w = p[(size_t)(3 * HID) + 1];
    }

    for (int t = 0; t < T_STEPS - 1; ++t) {
        float2 xp = make_float2(0.f, 0.f);
        if (lane == 0) xp = *(const float2*)&H[(size_t)(t + 1) * HID + c0];

        const char* slot = (const char*)hcomm +
                           (((size_t)(t & 1) * HID + 2 * (size_t)tid) << 3);
        v4i e;
        do {
            e = uncached_load16(slot);
        } while (e.y != t || e.w != t);

        *(float2*)&hlds[t & 1][2 * tid] =
            make_float2(__int_as_float(e.x), __int_as_float(e.z));
        __syncthreads();

        const float* hb = hlds[t & 1];
        float s0 = 0.f, s1 = 0.f;
#pragma unroll
        for (int k = 0; k < 8; ++k) {
            float4 hh = *(const float4*)&hb[4 * lane + 256 * k];
            s0 += hh.x * w0[k].x + hh.y * w0[k].y + hh.z * w0[k].z + hh.w * w0[k].w;
            s1 += hh.x * w1[k].x + hh.y * w1[k].y + hh.z * w1[k].z + hh.w * w1[k].w;
        }
#pragma unroll
        for (int m = 1; m < 64; m <<= 1) {
            s0 += __shfl_xor(s0, m, 64);
            s1 += __shfl_xor(s1, m, 64);
        }

        if (lane == 0) {
            float h0 = tanhf(xp.x + s0);
            float h1 = tanhf(xp.y + s1);
            v4i pub;
            pub.x = __float_as_int(h0); pub.y = t + 1;
            pub.z = __float_as_int(h1); pub.w = t + 1;
            uncached_store16((char*)hcomm +
                             (((size_t)((t + 1) & 1) * HID + (size_t)c0) << 3), pub);
            *(float2*)&H[(size_t)(t + 1) * HID + c0] = make_float2(h0, h1);
        }
    }
}

// ---------------------------------------------------------------------------
static void launch_r3_path(const float* X, const float* Wx, const float* Wh,
                           const float* b, float* H, void* d_ws, hipStream_t stream)
{
    unsigned long long* hcomm = (unsigned long long*)d_ws;
    hipMemsetAsync(H, 0, HID * sizeof(float), stream);
    hipMemsetAsync(d_ws, 0, 2 * HID * sizeof(unsigned long long), stream);

    dim3 ggrid(HID / BN, T_STEPS / BM);
    xproj_gemm<<<ggrid, 256, 0, stream>>>(X, Wx, b, H + HID);  // in-place XP

    const float* whp = Wh; float* hp = H; unsigned long long* cp = hcomm;
    void* args[] = { (void*)&whp, (void*)&hp, (void*)&cp };
    hipLaunchCooperativeKernel((const void*)rnn_scan_r3, dim3(NBLK_R3),
                               dim3(TPB_R3), args, 0, stream);
}

extern "C" void kernel_launch(void* const* d_in, const int* in_sizes, int n_in,
                              void* d_out, int out_size, void* d_ws, size_t ws_size,
                              hipStream_t stream)
{
    const float* X  = (const float*)d_in[0];
    const float* Wx = (const float*)d_in[1];
    const float* Wh = (const float*)d_in[2];
    const float* b  = (const float*)d_in[3];
    float* H = (float*)d_out;

    const size_t XP_BYTES = (size_t)(T_STEPS - 1) * HID * sizeof(float); // ~256 MiB
    const size_t XP_OFF   = 512 * 1024;
    const bool big_ws = ws_size >= XP_OFF + XP_BYTES;

    // Gate 1 (deterministic host query, stream-independent): can the fast
    // kernel be resident 1 block/CU? Catches any LDS/VGPR validation issue
    // BEFORE we commit the graph to the fast path.
    int nb = 0;
    bool fast_ok = big_ws &&
        (hipOccupancyMaxActiveBlocksPerMultiprocessor(&nb, (const void*)rnn_scan_fast,
                                                      256, 0) == hipSuccess) && nb >= 1;

    if (fast_ok) {
        unsigned long long* hcomm = (unsigned long long*)d_ws;  // 8 x 2 x HID
        float* XPb = (float*)((char*)d_ws + XP_OFF);

        hipMemsetAsync(H, 0, HID * sizeof(float), stream);      // h0 row
        hipMemsetAsync(d_ws, 0, 8 * 2 * HID * sizeof(unsigned long long), stream);

        dim3 ggrid(HID / BN, T_STEPS / BM);
        xproj_gemm<<<ggrid, 256, 0, stream>>>(X, Wx, b, XPb);

        const float* whp = Wh; const float* xpp = XPb;
        float* hp = H; unsigned long long* cp = hcomm;
        void* args[] = { (void*)&whp, (void*)&xpp, (void*)&hp, (void*)&cp };
        hipError_t err = hipLaunchCooperativeKernel((const void*)rnn_scan_fast,
                                                    dim3(256), dim3(256), args, 0, stream);
        // Gate 2: if the cooperative launch itself was rejected, fall back
        // in-stream to the proven R3 path (re-runs GEMM into H in-place).
        if (err != hipSuccess) {
            launch_r3_path(X, Wx, Wh, b, H, d_ws, stream);
        }
    } else {
        launch_r3_path(X, Wx, Wh, b, H, d_ws, stream);
    }
}

// Round 10
// 135182.983 us; speedup vs baseline: 1.0489x; 1.0489x over previous
//
#include <hip/hip_runtime.h>
#include <math.h>

#define T_STEPS 32768
#define HID 2048
#define EMB 2048

// ---------------------------------------------------------------------------
// Kernel A: XP[m] = X[m] @ Wx + b  (m = 0..T-2) -> XPout[m*HID + ...].
// Fast path: XPout = ws XP buffer. Fallback: XPout = H + HID (in-place R3).
// ---------------------------------------------------------------------------
#define BM 64
#define BN 64
#define BK 16

__global__ __launch_bounds__(256) void xproj_gemm(const float* __restrict__ X,
                                                  const float* __restrict__ Wx,
                                                  const float* __restrict__ bias,
                                                  float* __restrict__ XPout)
{
    __shared__ __align__(16) float As[BK][BM];
    __shared__ __align__(16) float Bs[BK][BN];

    const int tid = threadIdx.x;
    const int m0 = blockIdx.y * BM;
    const int n0 = blockIdx.x * BN;

    const int tn = tid & 15;
    const int tm = tid >> 4;
    const int am = tid >> 2;
    const int ak = (tid & 3) << 2;
    const int bk = tid >> 4;
    const int bn = (tid & 15) << 2;

    const int arow = m0 + am;
    const bool aval = arow < (T_STEPS - 1);

    float acc[4][4];
#pragma unroll
    for (int i = 0; i < 4; ++i)
#pragma unroll
        for (int j = 0; j < 4; ++j) acc[i][j] = 0.f;

    for (int k0 = 0; k0 < EMB; k0 += BK) {
        float4 av = make_float4(0.f, 0.f, 0.f, 0.f);
        if (aval) av = *(const float4*)&X[(size_t)arow * EMB + k0 + ak];
        float4 bv = *(const float4*)&Wx[(size_t)(k0 + bk) * HID + n0 + bn];

        __syncthreads();
        As[ak + 0][am] = av.x;
        As[ak + 1][am] = av.y;
        As[ak + 2][am] = av.z;
        As[ak + 3][am] = av.w;
        *(float4*)&Bs[bk][bn] = bv;
        __syncthreads();

#pragma unroll
        for (int k = 0; k < BK; ++k) {
            float4 a4 = *(const float4*)&As[k][tm << 2];
            float4 b4 = *(const float4*)&Bs[k][tn << 2];
            acc[0][0] += a4.x * b4.x; acc[0][1] += a4.x * b4.y;
            acc[0][2] += a4.x * b4.z; acc[0][3] += a4.x * b4.w;
            acc[1][0] += a4.y * b4.x; acc[1][1] += a4.y * b4.y;
            acc[1][2] += a4.y * b4.z; acc[1][3] += a4.y * b4.w;
            acc[2][0] += a4.z * b4.x; acc[2][1] += a4.z * b4.y;
            acc[2][2] += a4.z * b4.z; acc[2][3] += a4.z * b4.w;
            acc[3][0] += a4.w * b4.x; acc[3][1] += a4.w * b4.y;
            acc[3][2] += a4.w * b4.z; acc[3][3] += a4.w * b4.w;
        }
    }

    float4 bb = *(const float4*)&bias[n0 + (tn << 2)];
#pragma unroll
    for (int i = 0; i < 4; ++i) {
        int m = m0 + (tm << 2) + i;
        if (m < T_STEPS - 1) {
            float4 o;
            o.x = acc[i][0] + bb.x;
            o.y = acc[i][1] + bb.y;
            o.z = acc[i][2] + bb.z;
            o.w = acc[i][3] + bb.w;
            *(float4*)&XPout[(size_t)m * HID + n0 + (tn << 2)] = o;
        }
    }
}

// ---------------------------------------------------------------------------
typedef int v4i __attribute__((ext_vector_type(4)));
typedef int v2i __attribute__((ext_vector_type(2)));

__device__ __forceinline__ float dot4(float4 a, float4 b)
{
    return a.x * b.x + a.y * b.y + a.z * b.z + a.w * b.w;
}

__device__ __forceinline__ void poll2_sc0(const void* p, v4i& a, v4i& b)
{
    asm volatile("global_load_dwordx4 %0, %2, off sc0\n\t"
                 "global_load_dwordx4 %1, %2, off offset:16 sc0\n\t"
                 "s_waitcnt vmcnt(0)"
                 : "=&v"(a), "=&v"(b) : "v"(p) : "memory");
}
__device__ __forceinline__ void poll2_sys(const void* p, v4i& a, v4i& b)
{
    asm volatile("global_load_dwordx4 %0, %2, off sc0 sc1\n\t"
                 "global_load_dwordx4 %1, %2, off offset:16 sc0 sc1\n\t"
                 "s_waitcnt vmcnt(0)"
                 : "=&v"(a), "=&v"(b) : "v"(p) : "memory");
}
__device__ __forceinline__ void st8_sc0(void* p, v2i v)
{
    asm volatile("global_store_dwordx2 %0, %1, off sc0" :: "v"(p), "v"(v) : "memory");
}
__device__ __forceinline__ void st8_sys(void* p, v2i v)
{
    asm volatile("global_store_dwordx2 %0, %1, off sc0 sc1" :: "v"(p), "v"(v) : "memory");
}

__device__ __forceinline__ unsigned short bf16rne(float f)
{
    unsigned u = __float_as_uint(f);
    u += 0x7fffu + ((u >> 16) & 1u);
    return (unsigned short)(u >> 16);
}
__device__ __forceinline__ float bfup(unsigned short s)
{
    return __uint_as_float((unsigned)s << 16);
}

// ---------------------------------------------------------------------------
// Kernel B-fast: 8 replicated groups x 32 blocks x 512 thr (R8 protocol,
// proven correct; resources resized so NOTHING spills).
//   - block owns 64 cols; wave w (0..7) owns row segment [256w, 256w+256)
//   - rows [256w, 256w+176): fp32 in VGPRs, 44 float4 = 176 regs/lane
//     (launch_bounds(512,2) -> 256-reg cap; ~230 used -> NO spill, the R8 bug)
//   - rows [256w+176, 256w+256): bf16 in LDS, 80 KB, ushort4 lane-contiguous
//   - LDS total 98 KB -> 1 block/CU guaranteed; 256 blocks = all CUs
//   - group g=blockIdx&7 (RR dispatch => one XCD/group); intra-group
//     {val,step} handshake: publisher stores sys-then-sc0 (IF$ copy for
//     cross-XCD safety, fresh own-L2 line for co-located peers); consumer
//     polls sc0 with every-16th-round system probe (no hang mode).
//   - xp from read-only ws XP; only group 0 writes H.
//   - parity double-buffer + poll certificate; 2 barriers/step.
// ---------------------------------------------------------------------------
#define SCAN_TPB 512

__global__ __launch_bounds__(SCAN_TPB, 2) void rnn_scan_fast(const float* __restrict__ Wh,
                                                             const float* __restrict__ XP,
                                                             float* __restrict__ H,
                                                             unsigned long long* __restrict__ hcomm)
{
    __shared__ __align__(16) ushort4 Wb[8][20][64];  // 80 KB bf16 rows per wave-seg
    __shared__ __align__(16) float hlds[2][HID];     // 16 KB parity staging
    __shared__ float pacc[8][64];                    // 2 KB cross-wave partials

    const int tid = threadIdx.x;
    const int wave = tid >> 6;            // 0..7 = row segment
    const int lane = tid & 63;            // = local column
    const int g = blockIdx.x & 7;         // replica group (XCD under RR dispatch)
    const int rank = blockIdx.x >> 3;     // 0..31
    const int bc0 = rank * 64;            // block's first column
    unsigned long long* hcg = hcomm + (size_t)g * (2 * HID);

    // ---- VGPR weights: rows [256*wave, +176), col bc0+lane (static indices)
    float4 wreg[44];
    {
        const float* wp = Wh + (size_t)(256 * wave) * HID + bc0 + lane;
#pragma unroll
        for (int i = 0; i < 44; ++i) {
            wreg[i].x = wp[(size_t)(4 * i + 0) * HID];
            wreg[i].y = wp[(size_t)(4 * i + 1) * HID];
            wreg[i].z = wp[(size_t)(4 * i + 2) * HID];
            wreg[i].w = wp[(size_t)(4 * i + 3) * HID];
        }
    }
    // ---- LDS bf16 weights: rows [256*wave+176, +80) -> Wb[wave][j][lane]
    for (int j = 0; j < 20; ++j) {
        const float* p = Wh + (size_t)(256 * wave + 176 + 4 * j) * HID + bc0 + lane;
        ushort4 u;
        u.x = bf16rne(p[0]);
        u.y = bf16rne(p[(size_t)HID]);
        u.z = bf16rne(p[2 * (size_t)HID]);
        u.w = bf16rne(p[3 * (size_t)HID]);
        Wb[wave][j][lane] = u;
    }
    __syncthreads();

    for (int t = 0; t < T_STEPS - 1; ++t) {
        const int par = t & 1;

        // xp prefetch from read-only XP (latency hides under the poll)
        float xpv = 0.f;
        if (wave == 0) xpv = XP[(size_t)t * HID + bc0 + lane];

        // ---- poll own 4 {val,step} entries of h_t (32B, one vmcnt wait)
        const char* pb = (const char*)hcg + (((size_t)par * HID + 4 * (size_t)tid) << 3);
        v4i e0, e1;
        int round = 0;
        for (;;) {
            if ((round & 15) == 15) poll2_sys(pb, e0, e1);
            else                    poll2_sc0(pb, e0, e1);
            if (((e0.y ^ t) | (e0.w ^ t) | (e1.y ^ t) | (e1.w ^ t)) == 0) break;
            ++round;
        }

        v4i hv; hv.x = e0.x; hv.y = e0.z; hv.z = e1.x; hv.w = e1.z;
        *(v4i*)&hlds[par][4 * tid] = hv;
        __syncthreads();   // barrier 1: h_t staged; poll certificate

        // ---- partial dot for col bc0+lane over this wave's 256 rows
        const float* hb = &hlds[par][256 * wave];   // wave-uniform broadcasts
        float a0 = 0.f, a1 = 0.f;
#pragma unroll
        for (int i = 0; i < 44; i += 2) {
            a0 += dot4(wreg[i],     *(const float4*)&hb[4 * i]);
            a1 += dot4(wreg[i + 1], *(const float4*)&hb[4 * i + 4]);
        }
        float b0 = 0.f;
#pragma unroll
        for (int j = 0; j < 20; ++j) {
            ushort4 u = Wb[wave][j][lane];          // 8B/lane, 2-way alias (free)
            float4 q = *(const float4*)&hb[176 + 4 * j];
            b0 += bfup(u.x) * q.x + bfup(u.y) * q.y
                + bfup(u.z) * q.z + bfup(u.w) * q.w;
        }
        pacc[wave][lane] = (a0 + a1) + b0;
        __syncthreads();   // barrier 2: partials ready (reuse guarded by barrier 1)

        if (wave == 0) {
            float tot = ((pacc[0][lane] + pacc[1][lane]) + (pacc[2][lane] + pacc[3][lane]))
                      + ((pacc[4][lane] + pacc[5][lane]) + (pacc[6][lane] + pacc[7][lane]));
            float hvn = tanhf(xpv + tot);
            v2i e; e.x = __float_as_int(hvn); e.y = t + 1;
            char* pa = (char*)hcg + (((size_t)(par ^ 1) * HID + bc0 + lane) << 3);
            st8_sys(pa, e);   // IF$ copy (cross-XCD correctness)
            st8_sc0(pa, e);   // own-L2 line left fresh for co-located peers
            if (g == 0) H[(size_t)(t + 1) * HID + bc0 + lane] = hvn;
        }
    }
}

// ---------------------------------------------------------------------------
// Kernel B-fallback: verbatim R3 scan (PASSED at 139.8 ms).
// ---------------------------------------------------------------------------
#define NBLK_R3 64
#define TPB_R3 1024
#define CPB_R3 32
#define CPW_R3 2

__device__ __forceinline__ v4i uncached_load16(const void* p)
{
    v4i r;
    asm volatile("global_load_dwordx4 %0, %1, off sc0 sc1\n\t"
                 "s_waitcnt vmcnt(0)"
                 : "=v"(r) : "v"(p) : "memory");
    return r;
}
__device__ __forceinline__ void uncached_store16(void* p, v4i v)
{
    asm volatile("global_store_dwordx4 %0, %1, off sc0 sc1"
                 :: "v"(p), "v"(v) : "memory");
}

__global__ __launch_bounds__(TPB_R3, 4) void rnn_scan_r3(const float* __restrict__ Wh,
                                                         float* __restrict__ H,
                                                         unsigned long long* __restrict__ hcomm)
{
    __shared__ __align__(16) float hlds[2][HID];
    __shared__ float pad[18432];

    const int tid = threadIdx.x;
    const int wave = tid >> 6;
    const int lane = tid & 63;
    const int c0 = blockIdx.x * CPB_R3 + wave * CPW_R3;

    if ((((size_t)hcomm) >> 22) & 1) ((volatile float*)pad)[tid] = 0.f;

    float4 w0[8], w1[8];
#pragma unroll
    for (int k = 0; k < 8; ++k) {
        const int r = 4 * lane + 256 * k;
        const float* p = Wh + (size_t)r * HID + c0;
        w0[k].x = p[0];                     w1[k].x = p[1];
        w0[k].y = p[(size_t)HID];           w1[k].y = p[(size_t)HID + 1];
        w0[k].z = p[(size_t)(2 * HID)];     w1[k].z = p[(size_t)(2 * HID) + 1];
        w0[k].w = p[(size_t)(3 * HID)];     w1[k].w = p[(size_t)(3 * HID) + 1];
    }

    for (int t = 0; t < T_STEPS - 1; ++t) {
        float2 xp = make_float2(0.f, 0.f);
        if (lane == 0) xp = *(const float2*)&H[(size_t)(t + 1) * HID + c0];

        const char* slot = (const char*)hcomm +
                           (((size_t)(t & 1) * HID + 2 * (size_t)tid) << 3);
        v4i e;
        do {
            e = uncached_load16(slot);
        } while (e.y != t || e.w != t);

        *(float2*)&hlds[t & 1][2 * tid] =
            make_float2(__int_as_float(e.x), __int_as_float(e.z));
        __syncthreads();

        const float* hb = hlds[t & 1];
        float s0 = 0.f, s1 = 0.f;
#pragma unroll
        for (int k = 0; k < 8; ++k) {
            float4 hh = *(const float4*)&hb[4 * lane + 256 * k];
            s0 += hh.x * w0[k].x + hh.y * w0[k].y + hh.z * w0[k].z + hh.w * w0[k].w;
            s1 += hh.x * w1[k].x + hh.y * w1[k].y + hh.z * w1[k].z + hh.w * w1[k].w;
        }
#pragma unroll
        for (int m = 1; m < 64; m <<= 1) {
            s0 += __shfl_xor(s0, m, 64);
            s1 += __shfl_xor(s1, m, 64);
        }

        if (lane == 0) {
            float h0 = tanhf(xp.x + s0);
            float h1 = tanhf(xp.y + s1);
            v4i pub;
            pub.x = __float_as_int(h0); pub.y = t + 1;
            pub.z = __float_as_int(h1); pub.w = t + 1;
            uncached_store16((char*)hcomm +
                             (((size_t)((t + 1) & 1) * HID + (size_t)c0) << 3), pub);
            *(float2*)&H[(size_t)(t + 1) * HID + c0] = make_float2(h0, h1);
        }
    }
}

// ---------------------------------------------------------------------------
static void launch_r3_path(const float* X, const float* Wx, const float* Wh,
                           const float* b, float* H, void* d_ws, hipStream_t stream)
{
    unsigned long long* hcomm = (unsigned long long*)d_ws;
    hipMemsetAsync(H, 0, HID * sizeof(float), stream);
    hipMemsetAsync(d_ws, 0, 2 * HID * sizeof(unsigned long long), stream);

    dim3 ggrid(HID / BN, T_STEPS / BM);
    xproj_gemm<<<ggrid, 256, 0, stream>>>(X, Wx, b, H + HID);  // in-place XP

    const float* whp = Wh; float* hp = H; unsigned long long* cp = hcomm;
    void* args[] = { (void*)&whp, (void*)&hp, (void*)&cp };
    hipLaunchCooperativeKernel((const void*)rnn_scan_r3, dim3(NBLK_R3),
                               dim3(TPB_R3), args, 0, stream);
}

extern "C" void kernel_launch(void* const* d_in, const int* in_sizes, int n_in,
                              void* d_out, int out_size, void* d_ws, size_t ws_size,
                              hipStream_t stream)
{
    const float* X  = (const float*)d_in[0];
    const float* Wx = (const float*)d_in[1];
    const float* Wh = (const float*)d_in[2];
    const float* b  = (const float*)d_in[3];
    float* H = (float*)d_out;

    const size_t XP_BYTES = (size_t)(T_STEPS - 1) * HID * sizeof(float); // ~256 MiB
    const size_t XP_OFF   = 512 * 1024;
    const bool big_ws = ws_size >= XP_OFF + XP_BYTES;

    // Gate 1: fast kernel must be resident 1 block/CU (catches LDS/VGPR
    // validation issues BEFORE committing the graph to the fast path).
    int nb = 0;
    bool fast_ok = big_ws &&
        (hipOccupancyMaxActiveBlocksPerMultiprocessor(&nb, (const void*)rnn_scan_fast,
                                                      SCAN_TPB, 0) == hipSuccess) && nb >= 1;

    if (fast_ok) {
        unsigned long long* hcomm = (unsigned long long*)d_ws;  // 8 x 2 x HID
        float* XPb = (float*)((char*)d_ws + XP_OFF);

        hipMemsetAsync(H, 0, HID * sizeof(float), stream);      // h0 row
        hipMemsetAsync(d_ws, 0, 8 * 2 * HID * sizeof(unsigned long long), stream);

        dim3 ggrid(HID / BN, T_STEPS / BM);
        xproj_gemm<<<ggrid, 256, 0, stream>>>(X, Wx, b, XPb);

        const float* whp = Wh; const float* xpp = XPb;
        float* hp = H; unsigned long long* cp = hcomm;
        void* args[] = { (void*)&whp, (void*)&xpp, (void*)&hp, (void*)&cp };
        hipError_t err = hipLaunchCooperativeKernel((const void*)rnn_scan_fast,
                                                    dim3(256), dim3(SCAN_TPB), args, 0, stream);
        // Gate 2: cooperative launch rejected -> proven R3 path in-stream.
        if (err != hipSuccess) {
            launch_r3_path(X, Wx, Wh, b, H, d_ws, stream);
        }
    } else {
        launch_r3_path(X, Wx, Wh, b, H, d_ws, stream);
    }
}